// Round 7
// baseline (141.008 us; speedup 1.0000x reference)
//
#include <hip/hip_runtime.h>
#include <hip/hip_bf16.h>
#include <math.h>

#define CC 8
#define BB 4096
#define DD 512
#define SLOT_STRIDE (BB * DD)   // elements between (c,v) slots
#define NBLK (BB / 4)           // 1024 blocks, 4 batch columns each

constexpr float INV_T    = 10.0f;    // 1 / 0.1
constexpr float NORM_EPS = 1e-12f;

typedef __attribute__((ext_vector_type(8))) short bf16x8;  // 8 bf16 (4 VGPRs)
typedef __attribute__((ext_vector_type(4))) float f32x4;   // 4 fp32 acc / loads

__device__ __forceinline__ short f2bf(float x) {           // RNE, proven in R4
    union { __hip_bfloat16 h; short s; } u;
    u.h = __float2bfloat16(x);
    return u.s;
}

// One wave per batch column b. The 16 vectors (slots) of column b form
// X (16 x 512). Gram G = X X^T via 16x16x32 bf16 MFMA with A-frag == B-frag
// (identical lane mapping: row/col = lane&15); any shared element->k
// permutation cancels exactly, so load order is chosen for coalescing.
// Norms exact in f32. Last-arriving block reduces the per-block partials.
// Cross-XCD visibility: producers release via agent-scope RMW; the consumer
// reads partials with agent-scope atomic loads (bypass stale per-XCD L2 —
// plain loads after the counter RMW read stale lines; cost R6 -0.27 absmax).
__global__ __launch_bounds__(256, 4)   // cap VGPR at 128 -> 4 waves/SIMD
void ntxent_mfma(const float* __restrict__ inp, float* __restrict__ partial,
                 unsigned int* __restrict__ counter, float* __restrict__ out) {
    const int lane = threadIdx.x & 63;
    const int wv   = threadIdx.x >> 6;      // wave in block: 0..3
    const int b    = blockIdx.x * 4 + wv;   // batch column
    const int slot = lane & 15;             // vector index = MFMA row & col
    const int kg   = lane >> 4;             // quarter-wave 0..3

    const f32x4* p4 = reinterpret_cast<const f32x4*>(
        inp + (size_t)slot * SLOT_STRIDE + (size_t)b * DD);

    f32x4 acc0 = {0.f, 0.f, 0.f, 0.f};      // even chunks
    f32x4 acc1 = {0.f, 0.f, 0.f, 0.f};      // odd chunks (independent chain)
    float n2a = 0.f, n2b = 0.f;             // f32 partials of ||x_slot||^2

    // chunk t covers elements [32t, 32t+32): lane takes 32t+4kg+[0..4) and
    // 32t+16+4kg+[0..4). Streaming-once data -> non-temporal loads.
#pragma unroll
    for (int tt = 0; tt < 8; ++tt) {
#pragma unroll
        for (int h = 0; h < 2; ++h) {
            const int t = 2 * tt + h;
            const f32x4 lo = __builtin_nontemporal_load(&p4[8 * t + kg]);
            const f32x4 hi = __builtin_nontemporal_load(&p4[8 * t + 4 + kg]);
            n2a = fmaf(lo.x, lo.x, n2a);
            n2a = fmaf(lo.y, lo.y, n2a);
            n2a = fmaf(lo.z, lo.z, n2a);
            n2a = fmaf(lo.w, lo.w, n2a);
            n2b = fmaf(hi.x, hi.x, n2b);
            n2b = fmaf(hi.y, hi.y, n2b);
            n2b = fmaf(hi.z, hi.z, n2b);
            n2b = fmaf(hi.w, hi.w, n2b);
            bf16x8 f;
            f[0] = f2bf(lo.x); f[1] = f2bf(lo.y); f[2] = f2bf(lo.z); f[3] = f2bf(lo.w);
            f[4] = f2bf(hi.x); f[5] = f2bf(hi.y); f[6] = f2bf(hi.z); f[7] = f2bf(hi.w);
            if (h == 0)
                acc0 = __builtin_amdgcn_mfma_f32_16x16x32_bf16(f, f, acc0, 0, 0, 0);
            else
                acc1 = __builtin_amdgcn_mfma_f32_16x16x32_bf16(f, f, acc1, 0, 0, 0);
        }
    }
    const f32x4 acc = acc0 + acc1;

    // exact f32 norms: lanes {slot, slot+16, slot+32, slot+48} cover slot fully
    float n2 = n2a + n2b;
    n2 += __shfl_xor(n2, 16);
    n2 += __shfl_xor(n2, 32);
    const float invc = 1.0f / fmaxf(sqrtf(n2), NORM_EPS);  // 1/||x_slot||

    // C/D layout (m89): lane holds G[4kg + r][slot] in acc[r].
    // Even rows 4kg, 4kg+2 are anchors (crops 2kg, 2kg+1, view 0).
    const float inv0 = __shfl(invc, 4 * kg);       // 1/||x_{4kg}||
    const float inv2 = __shfl(invc, 4 * kg + 2);   // 1/||x_{4kg+2}||

    const float s0 = acc[0] * inv0 * invc * INV_T;  // sim[anchor 2kg  ][slot]
    const float s2 = acc[2] * inv2 * invc * INV_T;  // sim[anchor 2kg+1][slot]

    // positives: sim[2a][2a+1] lives on the lane whose slot == anchor_slot+1
    const int gbase = kg << 4;
    const float pos0 = __shfl(s0, gbase + 4 * kg + 1);
    const float pos1 = __shfl(s2, gbase + 4 * kg + 3);

    // exclude same-crop targets (slots 2a, 2a+1), sum exp over remaining 14
    float e0 = ((slot >> 1) == 2 * kg)     ? 0.f : __expf(s0 - pos0);
    float e1 = ((slot >> 1) == 2 * kg + 1) ? 0.f : __expf(s2 - pos1);
#pragma unroll
    for (int m = 1; m < 16; m <<= 1) {
        e0 += __shfl_xor(e0, m);
        e1 += __shfl_xor(e1, m);
    }
    // loss[a][b] = log(1 + S_a); sum 2 anchors of this group, then 4 groups
    float l = __logf(1.0f + e0) + __logf(1.0f + e1);
    l += __shfl_xor(l, 16);
    l += __shfl_xor(l, 32);   // sum over all 8 anchors for this b

    __shared__ float s_wsum[4];
    __shared__ bool  s_last;
    if (lane == 0) s_wsum[wv] = l;
    __syncthreads();
    if (threadIdx.x == 0) {
        partial[blockIdx.x] = s_wsum[0] + s_wsum[1] + s_wsum[2] + s_wsum[3];
        __threadfence();  // write back producer L2 before arrival
        const unsigned int old = __hip_atomic_fetch_add(
            counter, 1u, __ATOMIC_ACQ_REL, __HIP_MEMORY_SCOPE_AGENT);
        s_last = (old == NBLK - 1);
    }
    __syncthreads();
    if (!s_last) return;

    // last block: agent-scope atomic loads bypass this XCD's (possibly
    // stale) L1/L2 and read from the device coherence point.
    const int tid = threadIdx.x;
    float s = 0.f;
#pragma unroll
    for (int j = 0; j < 4; ++j)
        s += __hip_atomic_load(&partial[tid + 256 * j],
                               __ATOMIC_RELAXED, __HIP_MEMORY_SCOPE_AGENT);
#pragma unroll
    for (int m = 1; m < 64; m <<= 1) s += __shfl_xor(s, m);
    __shared__ float ws[4];
    if ((tid & 63) == 0) ws[tid >> 6] = s;
    __syncthreads();
    if (tid == 0)
        out[0] = (ws[0] + ws[1] + ws[2] + ws[3]) * (1.0f / (float)(CC * BB));
}

extern "C" void kernel_launch(void* const* d_in, const int* in_sizes, int n_in,
                              void* d_out, int out_size, void* d_ws, size_t ws_size,
                              hipStream_t stream) {
    const float* inp = (const float*)d_in[0];
    float* out      = (float*)d_out;
    float* partial  = (float*)d_ws;                       // NBLK floats
    unsigned int* counter =
        (unsigned int*)((char*)d_ws + NBLK * sizeof(float));
    (void)hipMemsetAsync(counter, 0, sizeof(unsigned int), stream);  // graph-safe
    ntxent_mfma<<<dim3(NBLK), dim3(256), 0, stream>>>(inp, partial, counter, out);
}

// Round 8
// 90.347 us; speedup vs baseline: 1.5607x; 1.5607x over previous
//
#include <hip/hip_runtime.h>
#include <hip/hip_bf16.h>
#include <math.h>

#define CC 8
#define BB 4096
#define DD 512
#define SLOT_STRIDE (BB * DD)   // elements between (c,v) slots
#define NBLK (BB / 4)           // 1024 blocks, 4 batch columns each

constexpr float INV_T    = 10.0f;    // 1 / 0.1
constexpr float NORM_EPS = 1e-12f;

typedef __attribute__((ext_vector_type(8))) short bf16x8;  // 8 bf16 (4 VGPRs)
typedef __attribute__((ext_vector_type(4))) float f32x4;   // 4 fp32 acc / loads

__device__ __forceinline__ short f2bf(float x) {           // RNE, proven in R4
    union { __hip_bfloat16 h; short s; } u;
    u.h = __float2bfloat16(x);
    return u.s;
}

// One wave per batch column b. The 16 vectors (slots) of column b form
// X (16 x 512). Gram G = X X^T via 16x16x32 bf16 MFMA with A-frag == B-frag
// (identical lane mapping: row/col = lane&15); any shared element->k
// permutation cancels exactly, so load order is chosen for coalescing:
// per (slot, chunk) the 8 lane-requests tile one full 128B line.
// Norms exact in f32. Last-arriving block reduces per-block partials
// (agent-scope release/acquire — R7-proven correct across XCDs).
// NOTE (R7 lesson): __builtin_nontemporal_load here collapsed VGPR use to 32,
// killed load batching (4.7x regression). Plain loads restore deep hoisting.
__global__ __launch_bounds__(256, 4)   // cap VGPR at 128 -> 4 waves/SIMD
void ntxent_mfma(const float* __restrict__ inp, float* __restrict__ partial,
                 unsigned int* __restrict__ counter, float* __restrict__ out) {
    const int lane = threadIdx.x & 63;
    const int wv   = threadIdx.x >> 6;      // wave in block: 0..3
    const int b    = blockIdx.x * 4 + wv;   // batch column
    const int slot = lane & 15;             // vector index = MFMA row & col
    const int kg   = lane >> 4;             // quarter-wave 0..3

    const f32x4* p4 = reinterpret_cast<const f32x4*>(
        inp + (size_t)slot * SLOT_STRIDE + (size_t)b * DD);

    f32x4 acc0 = {0.f, 0.f, 0.f, 0.f};      // even chunks
    f32x4 acc1 = {0.f, 0.f, 0.f, 0.f};      // odd chunks (independent chain)
    float n2a = 0.f, n2b = 0.f;             // f32 partials of ||x_slot||^2

    // chunk t covers elements [32t, 32t+32): lane takes 32t+4kg+[0..4) and
    // 32t+16+4kg+[0..4)  ->  p4[8t+kg] and p4[8t+4+kg]
#pragma unroll
    for (int tt = 0; tt < 8; ++tt) {
#pragma unroll
        for (int h = 0; h < 2; ++h) {
            const int t = 2 * tt + h;
            const f32x4 lo = p4[8 * t + kg];
            const f32x4 hi = p4[8 * t + 4 + kg];
            n2a = fmaf(lo.x, lo.x, n2a);
            n2a = fmaf(lo.y, lo.y, n2a);
            n2a = fmaf(lo.z, lo.z, n2a);
            n2a = fmaf(lo.w, lo.w, n2a);
            n2b = fmaf(hi.x, hi.x, n2b);
            n2b = fmaf(hi.y, hi.y, n2b);
            n2b = fmaf(hi.z, hi.z, n2b);
            n2b = fmaf(hi.w, hi.w, n2b);
            bf16x8 f;
            f[0] = f2bf(lo.x); f[1] = f2bf(lo.y); f[2] = f2bf(lo.z); f[3] = f2bf(lo.w);
            f[4] = f2bf(hi.x); f[5] = f2bf(hi.y); f[6] = f2bf(hi.z); f[7] = f2bf(hi.w);
            if (h == 0)
                acc0 = __builtin_amdgcn_mfma_f32_16x16x32_bf16(f, f, acc0, 0, 0, 0);
            else
                acc1 = __builtin_amdgcn_mfma_f32_16x16x32_bf16(f, f, acc1, 0, 0, 0);
        }
    }
    const f32x4 acc = acc0 + acc1;

    // exact f32 norms: lanes {slot, slot+16, slot+32, slot+48} cover slot fully
    float n2 = n2a + n2b;
    n2 += __shfl_xor(n2, 16);
    n2 += __shfl_xor(n2, 32);
    const float invc = 1.0f / fmaxf(sqrtf(n2), NORM_EPS);  // 1/||x_slot||

    // C/D layout (m89): lane holds G[4kg + r][slot] in acc[r].
    // Even rows 4kg, 4kg+2 are anchors (crops 2kg, 2kg+1, view 0).
    const float inv0 = __shfl(invc, 4 * kg);       // 1/||x_{4kg}||
    const float inv2 = __shfl(invc, 4 * kg + 2);   // 1/||x_{4kg+2}||

    const float s0 = acc[0] * inv0 * invc * INV_T;  // sim[anchor 2kg  ][slot]
    const float s2 = acc[2] * inv2 * invc * INV_T;  // sim[anchor 2kg+1][slot]

    // positives: sim[2a][2a+1] lives on the lane whose slot == anchor_slot+1
    const int gbase = kg << 4;
    const float pos0 = __shfl(s0, gbase + 4 * kg + 1);
    const float pos1 = __shfl(s2, gbase + 4 * kg + 3);

    // exclude same-crop targets (slots 2a, 2a+1), sum exp over remaining 14
    float e0 = ((slot >> 1) == 2 * kg)     ? 0.f : __expf(s0 - pos0);
    float e1 = ((slot >> 1) == 2 * kg + 1) ? 0.f : __expf(s2 - pos1);
#pragma unroll
    for (int m = 1; m < 16; m <<= 1) {
        e0 += __shfl_xor(e0, m);
        e1 += __shfl_xor(e1, m);
    }
    // loss[a][b] = log(1 + S_a); sum 2 anchors of this group, then 4 groups
    float l = __logf(1.0f + e0) + __logf(1.0f + e1);
    l += __shfl_xor(l, 16);
    l += __shfl_xor(l, 32);   // sum over all 8 anchors for this b

    __shared__ float s_wsum[4];
    __shared__ bool  s_last;
    if (lane == 0) s_wsum[wv] = l;
    __syncthreads();
    if (threadIdx.x == 0) {
        partial[blockIdx.x] = s_wsum[0] + s_wsum[1] + s_wsum[2] + s_wsum[3];
        __threadfence();  // write back producer L2 before arrival
        const unsigned int old = __hip_atomic_fetch_add(
            counter, 1u, __ATOMIC_ACQ_REL, __HIP_MEMORY_SCOPE_AGENT);
        s_last = (old == NBLK - 1);
    }
    __syncthreads();
    if (!s_last) return;

    // last block: agent-scope atomic loads bypass this XCD's (possibly
    // stale) L1/L2 and read from the device coherence point.
    const int tid = threadIdx.x;
    float s = 0.f;
#pragma unroll
    for (int j = 0; j < 4; ++j)
        s += __hip_atomic_load(&partial[tid + 256 * j],
                               __ATOMIC_RELAXED, __HIP_MEMORY_SCOPE_AGENT);
#pragma unroll
    for (int m = 1; m < 64; m <<= 1) s += __shfl_xor(s, m);
    __shared__ float ws[4];
    if ((tid & 63) == 0) ws[tid >> 6] = s;
    __syncthreads();
    if (tid == 0)
        out[0] = (ws[0] + ws[1] + ws[2] + ws[3]) * (1.0f / (float)(CC * BB));
}

extern "C" void kernel_launch(void* const* d_in, const int* in_sizes, int n_in,
                              void* d_out, int out_size, void* d_ws, size_t ws_size,
                              hipStream_t stream) {
    const float* inp = (const float*)d_in[0];
    float* out      = (float*)d_out;
    float* partial  = (float*)d_ws;                       // NBLK floats
    unsigned int* counter =
        (unsigned int*)((char*)d_ws + NBLK * sizeof(float));
    (void)hipMemsetAsync(counter, 0, sizeof(unsigned int), stream);  // graph-safe
    ntxent_mfma<<<dim3(NBLK), dim3(256), 0, stream>>>(inp, partial, counter, out);
}

// Round 9
// 31.839 us; speedup vs baseline: 4.4287x; 2.8376x over previous
//
#include <hip/hip_runtime.h>
#include <hip/hip_bf16.h>
#include <math.h>

#define CC 8
#define BB 4096
#define DD 512
#define SLOT_STRIDE (BB * DD)   // elements between (c,v) slots
#define NBLK (BB / 2)           // 2048 blocks, 2 batch columns each

constexpr float INV_T    = 10.0f;    // 1 / 0.1
constexpr float NORM_EPS = 1e-12f;

typedef __attribute__((ext_vector_type(8))) short bf16x8;  // 8 bf16 (4 VGPRs)
typedef __attribute__((ext_vector_type(4))) float f32x4;   // 4 fp32 acc / loads

__device__ __forceinline__ short f2bf(float x) {           // RNE, proven in R4
    union { __hip_bfloat16 h; short s; } u;
    u.h = __float2bfloat16(x);
    return u.s;
}

// Two waves per batch column b (K split 256+256), two columns per block.
// The 16 vectors (slots) of column b form X (16 x 512); Gram G = X X^T via
// 16x16x32 bf16 MFMA with A-frag == B-frag (identical lane mapping), so any
// shared element->k permutation cancels exactly. Partner waves combine their
// half-Gram + half-norm^2 via one LDS exchange; even wave runs the epilogue.
// K-split doubles resident waves/CU to the 32-wave HW cap (R8 showed
// VALUBusy 1.5% / VGPR 32 -> latency-bound, TLP-starved at 16 waves/CU).
// No cross-block sync: per-block partial + tiny second kernel (R7/R8 lesson:
// per-block agent-scope fences cost ~100us in per-XCD L2 writebacks).
__global__ __launch_bounds__(256, 8)   // cap VGPR at 64 -> 8 waves/SIMD
void ntxent_mfma(const float* __restrict__ inp, float* __restrict__ partial) {
    const int lane = threadIdx.x & 63;
    const int wv2  = (threadIdx.x >> 6) & 1;   // K-half of this wave
    const int pr   = threadIdx.x >> 7;         // column pair 0/1
    const int b    = blockIdx.x * 2 + pr;      // batch column
    const int slot = lane & 15;                // vector index = MFMA row & col
    const int kg   = lane >> 4;                // quarter-wave 0..3

    const f32x4* p4 = reinterpret_cast<const f32x4*>(
        inp + (size_t)slot * SLOT_STRIDE + (size_t)b * DD);

    f32x4 acc0 = {0.f, 0.f, 0.f, 0.f};
    f32x4 acc1 = {0.f, 0.f, 0.f, 0.f};
    float n2a = 0.f, n2b = 0.f;

    // chunk t covers elements [32t, 32t+32): lane takes 32t+4kg+[0..4) and
    // 32t+16+4kg+[0..4). This wave: t in [8*wv2, 8*wv2+8).
    const int t0 = 8 * wv2;
#pragma unroll
    for (int tt = 0; tt < 4; ++tt) {
#pragma unroll
        for (int h = 0; h < 2; ++h) {
            const int t = t0 + 2 * tt + h;
            const f32x4 lo = p4[8 * t + kg];
            const f32x4 hi = p4[8 * t + 4 + kg];
            n2a = fmaf(lo.x, lo.x, n2a);
            n2a = fmaf(lo.y, lo.y, n2a);
            n2a = fmaf(lo.z, lo.z, n2a);
            n2a = fmaf(lo.w, lo.w, n2a);
            n2b = fmaf(hi.x, hi.x, n2b);
            n2b = fmaf(hi.y, hi.y, n2b);
            n2b = fmaf(hi.z, hi.z, n2b);
            n2b = fmaf(hi.w, hi.w, n2b);
            bf16x8 f;
            f[0] = f2bf(lo.x); f[1] = f2bf(lo.y); f[2] = f2bf(lo.z); f[3] = f2bf(lo.w);
            f[4] = f2bf(hi.x); f[5] = f2bf(hi.y); f[6] = f2bf(hi.z); f[7] = f2bf(hi.w);
            if (h == 0)
                acc0 = __builtin_amdgcn_mfma_f32_16x16x32_bf16(f, f, acc0, 0, 0, 0);
            else
                acc1 = __builtin_amdgcn_mfma_f32_16x16x32_bf16(f, f, acc1, 0, 0, 0);
        }
    }
    f32x4 acc = acc0 + acc1;            // half-Gram (this wave's K-half)
    float n2  = n2a + n2b;              // half-norm^2 partial

    // combine the two K-halves: odd wave publishes, even wave accumulates.
    // stride 5 floats: lanes i, i+32 share a bank -> 2-way (free).
    __shared__ float lds[2][64][5];
    __shared__ float s_wsum[2];
    if (wv2 == 1) {
        lds[pr][lane][0] = acc[0];
        lds[pr][lane][1] = acc[1];
        lds[pr][lane][2] = acc[2];
        lds[pr][lane][3] = acc[3];
        lds[pr][lane][4] = n2;
    }
    __syncthreads();

    if (wv2 == 0) {
        acc[0] += lds[pr][lane][0];
        acc[1] += lds[pr][lane][1];
        acc[2] += lds[pr][lane][2];
        acc[3] += lds[pr][lane][3];
        n2     += lds[pr][lane][4];

        // exact f32 norms: lanes {slot, +16, +32, +48} cover slot fully
        n2 += __shfl_xor(n2, 16);
        n2 += __shfl_xor(n2, 32);
        const float invc = 1.0f / fmaxf(sqrtf(n2), NORM_EPS);  // 1/||x_slot||

        // C/D layout (m89): lane holds G[4kg + r][slot] in acc[r].
        const float inv0 = __shfl(invc, 4 * kg);       // 1/||x_{4kg}||
        const float inv2 = __shfl(invc, 4 * kg + 2);   // 1/||x_{4kg+2}||

        const float s0 = acc[0] * inv0 * invc * INV_T;  // sim[anchor 2kg  ][slot]
        const float s2 = acc[2] * inv2 * invc * INV_T;  // sim[anchor 2kg+1][slot]

        // positives: sim[2a][2a+1] on the lane whose slot == anchor_slot+1
        const int gbase = kg << 4;
        const float pos0 = __shfl(s0, gbase + 4 * kg + 1);
        const float pos1 = __shfl(s2, gbase + 4 * kg + 3);

        float e0 = ((slot >> 1) == 2 * kg)     ? 0.f : __expf(s0 - pos0);
        float e1 = ((slot >> 1) == 2 * kg + 1) ? 0.f : __expf(s2 - pos1);
#pragma unroll
        for (int m = 1; m < 16; m <<= 1) {
            e0 += __shfl_xor(e0, m);
            e1 += __shfl_xor(e1, m);
        }
        float l = __logf(1.0f + e0) + __logf(1.0f + e1);
        l += __shfl_xor(l, 16);
        l += __shfl_xor(l, 32);   // sum over all 8 anchors for column b

        if (lane == 0) s_wsum[pr] = l;
    }
    __syncthreads();
    if (threadIdx.x == 0) partial[blockIdx.x] = s_wsum[0] + s_wsum[1];
}

// Sum the 2048 per-block partials -> scalar loss. One block.
__global__ __launch_bounds__(256)
void ntxent_reduce(const float* __restrict__ partial, float* __restrict__ out) {
    const int tid = threadIdx.x;
    const f32x4* pv = reinterpret_cast<const f32x4*>(partial);  // 512 vec4
    const f32x4 v0 = pv[tid];
    const f32x4 v1 = pv[tid + 256];
    float s = v0.x + v0.y + v0.z + v0.w + v1.x + v1.y + v1.z + v1.w;
#pragma unroll
    for (int m = 1; m < 64; m <<= 1) s += __shfl_xor(s, m);
    __shared__ float ws[4];
    if ((tid & 63) == 0) ws[tid >> 6] = s;
    __syncthreads();
    if (tid == 0)
        out[0] = (ws[0] + ws[1] + ws[2] + ws[3]) * (1.0f / (float)(CC * BB));
}

extern "C" void kernel_launch(void* const* d_in, const int* in_sizes, int n_in,
                              void* d_out, int out_size, void* d_ws, size_t ws_size,
                              hipStream_t stream) {
    const float* inp = (const float*)d_in[0];
    float* out      = (float*)d_out;
    float* partial  = (float*)d_ws;   // NBLK floats, fully rewritten every call
    ntxent_mfma<<<dim3(NBLK), dim3(256), 0, stream>>>(inp, partial);
    ntxent_reduce<<<dim3(1), dim3(256), 0, stream>>>(partial, out);
}

// Round 10
// 28.298 us; speedup vs baseline: 4.9830x; 1.1252x over previous
//
#include <hip/hip_runtime.h>
#include <hip/hip_bf16.h>
#include <math.h>

#define CC 8
#define BB 4096
#define DD 512
#define SLOT_STRIDE (BB * DD)   // elements between (c,v) slots
#define NBLK (BB / 4)           // 1024 blocks, 4 batch columns each

constexpr float INV_T    = 10.0f;    // 1 / 0.1
constexpr float NORM_EPS = 1e-12f;

typedef __attribute__((ext_vector_type(8))) short bf16x8;  // 8 bf16 (4 VGPRs)
typedef __attribute__((ext_vector_type(4))) float f32x4;   // 4 fp32 acc / loads

__device__ __forceinline__ short f2bf(float x) {           // RNE, proven in R4
    union { __hip_bfloat16 h; short s; } u;
    u.h = __float2bfloat16(x);
    return u.s;
}

// One wave per batch column b (R4 structure: 4 columns/block, two-kernel
// reduction — 29.7us proven; R9 falsified occupancy as the limiter).
// R10 experiment: hoist ALL 32 float4 loads into registers (static-indexed,
// fully unrolled) BEFORE the cvt/norm/MFMA phase, so the wave issues its
// entire 32KB read burst back-to-back like the 7TB/s fill kernels, instead
// of dribbling loads between compute. ~170 VGPR -> launch_bounds(256,2):
// 8 waves/CU x 32KB outstanding = 256KB/CU >> BW*latency (~10KB) -- ample.
// Gram G = X X^T via 16x16x32 bf16 MFMA with A-frag == B-frag (identical
// lane mapping row/col = lane&15); shared element->k permutation cancels.
// Norms exact in f32. No fences/atomics (R7/R8 lesson: per-block agent-scope
// coherence costs ~100us in per-XCD L2 writebacks).
__global__ __launch_bounds__(256, 2)
void ntxent_mfma(const float* __restrict__ inp, float* __restrict__ partial) {
    const int lane = threadIdx.x & 63;
    const int wv   = threadIdx.x >> 6;      // wave in block: 0..3
    const int b    = blockIdx.x * 4 + wv;   // batch column
    const int slot = lane & 15;             // vector index = MFMA row & col
    const int kg   = lane >> 4;             // quarter-wave 0..3

    const f32x4* p4 = reinterpret_cast<const f32x4*>(
        inp + (size_t)slot * SLOT_STRIDE + (size_t)b * DD);

    // ---- phase 1: issue all 32 loads back-to-back into registers ----
    // chunk t covers elements [32t, 32t+32): lane takes 32t+4kg+[0..4) and
    // 32t+16+4kg+[0..4)  ->  p4[8t+kg] and p4[8t+4+kg]
    f32x4 L[16], H[16];
#pragma unroll
    for (int t = 0; t < 16; ++t) {
        L[t] = p4[8 * t + kg];
        H[t] = p4[8 * t + 4 + kg];
    }

    // ---- phase 2: norms + bf16 convert + Gram MFMAs ----
    f32x4 acc0 = {0.f, 0.f, 0.f, 0.f};      // even chunks
    f32x4 acc1 = {0.f, 0.f, 0.f, 0.f};      // odd chunks (independent chain)
    float n2a = 0.f, n2b = 0.f;
#pragma unroll
    for (int t = 0; t < 16; ++t) {
        const f32x4 lo = L[t];
        const f32x4 hi = H[t];
        n2a = fmaf(lo.x, lo.x, n2a);
        n2a = fmaf(lo.y, lo.y, n2a);
        n2a = fmaf(lo.z, lo.z, n2a);
        n2a = fmaf(lo.w, lo.w, n2a);
        n2b = fmaf(hi.x, hi.x, n2b);
        n2b = fmaf(hi.y, hi.y, n2b);
        n2b = fmaf(hi.z, hi.z, n2b);
        n2b = fmaf(hi.w, hi.w, n2b);
        bf16x8 f;
        f[0] = f2bf(lo.x); f[1] = f2bf(lo.y); f[2] = f2bf(lo.z); f[3] = f2bf(lo.w);
        f[4] = f2bf(hi.x); f[5] = f2bf(hi.y); f[6] = f2bf(hi.z); f[7] = f2bf(hi.w);
        if (t & 1)
            acc1 = __builtin_amdgcn_mfma_f32_16x16x32_bf16(f, f, acc1, 0, 0, 0);
        else
            acc0 = __builtin_amdgcn_mfma_f32_16x16x32_bf16(f, f, acc0, 0, 0, 0);
    }
    const f32x4 acc = acc0 + acc1;

    // exact f32 norms: lanes {slot, slot+16, slot+32, slot+48} cover slot fully
    float n2 = n2a + n2b;
    n2 += __shfl_xor(n2, 16);
    n2 += __shfl_xor(n2, 32);
    const float invc = 1.0f / fmaxf(sqrtf(n2), NORM_EPS);  // 1/||x_slot||

    // C/D layout (m89): lane holds G[4kg + r][slot] in acc[r].
    // Even rows 4kg, 4kg+2 are anchors (crops 2kg, 2kg+1, view 0).
    const float inv0 = __shfl(invc, 4 * kg);       // 1/||x_{4kg}||
    const float inv2 = __shfl(invc, 4 * kg + 2);   // 1/||x_{4kg+2}||

    const float s0 = acc[0] * inv0 * invc * INV_T;  // sim[anchor 2kg  ][slot]
    const float s2 = acc[2] * inv2 * invc * INV_T;  // sim[anchor 2kg+1][slot]

    // positives: sim[2a][2a+1] lives on the lane whose slot == anchor_slot+1
    const int gbase = kg << 4;
    const float pos0 = __shfl(s0, gbase + 4 * kg + 1);
    const float pos1 = __shfl(s2, gbase + 4 * kg + 3);

    // exclude same-crop targets (slots 2a, 2a+1), sum exp over remaining 14
    float e0 = ((slot >> 1) == 2 * kg)     ? 0.f : __expf(s0 - pos0);
    float e1 = ((slot >> 1) == 2 * kg + 1) ? 0.f : __expf(s2 - pos1);
#pragma unroll
    for (int m = 1; m < 16; m <<= 1) {
        e0 += __shfl_xor(e0, m);
        e1 += __shfl_xor(e1, m);
    }
    // loss[a][b] = log(1 + S_a); sum 2 anchors of this group, then 4 groups
    float l = __logf(1.0f + e0) + __logf(1.0f + e1);
    l += __shfl_xor(l, 16);
    l += __shfl_xor(l, 32);   // sum over all 8 anchors for this b

    __shared__ float s_wsum[4];
    if (lane == 0) s_wsum[wv] = l;
    __syncthreads();
    if (threadIdx.x == 0)
        partial[blockIdx.x] = s_wsum[0] + s_wsum[1] + s_wsum[2] + s_wsum[3];
}

// Sum the 1024 per-block partials -> scalar loss. One block.
__global__ __launch_bounds__(256)
void ntxent_reduce(const float* __restrict__ partial, float* __restrict__ out) {
    const int tid = threadIdx.x;
    const f32x4 v = reinterpret_cast<const f32x4*>(partial)[tid];  // 256*4
    float s = v.x + v.y + v.z + v.w;
#pragma unroll
    for (int m = 1; m < 64; m <<= 1) s += __shfl_xor(s, m);
    __shared__ float ws[4];
    if ((tid & 63) == 0) ws[tid >> 6] = s;
    __syncthreads();
    if (tid == 0)
        out[0] = (ws[0] + ws[1] + ws[2] + ws[3]) * (1.0f / (float)(CC * BB));
}

extern "C" void kernel_launch(void* const* d_in, const int* in_sizes, int n_in,
                              void* d_out, int out_size, void* d_ws, size_t ws_size,
                              hipStream_t stream) {
    const float* inp = (const float*)d_in[0];
    float* out      = (float*)d_out;
    float* partial  = (float*)d_ws;   // NBLK floats, fully rewritten every call
    ntxent_mfma<<<dim3(NBLK), dim3(256), 0, stream>>>(inp, partial);
    ntxent_reduce<<<dim3(1), dim3(256), 0, stream>>>(partial, out);
}

// Round 11
// 27.868 us; speedup vs baseline: 5.0598x; 1.0154x over previous
//
#include <hip/hip_runtime.h>
#include <hip/hip_bf16.h>
#include <math.h>

#define CC 8
#define BB 4096
#define DD 512
#define SLOT_STRIDE (BB * DD)   // elements between (c,v) slots
#define NBLK (BB / 8)           // 512 blocks, 8 columns each (2 per wave)

constexpr float INV_T    = 10.0f;    // 1 / 0.1
constexpr float NORM_EPS = 1e-12f;

typedef __attribute__((ext_vector_type(8))) short bf16x8;  // 8 bf16 (4 VGPRs)
typedef __attribute__((ext_vector_type(4))) float f32x4;   // 4 fp32 acc / loads

__device__ __forceinline__ short f2bf(float x) {           // RNE, proven in R4
    union { __hip_bfloat16 h; short s; } u;
    u.h = __float2bfloat16(x);
    return u.s;
}

// One wave per batch column (2 columns sequentially per wave -> single
// occupancy pass: 512 blocks x 2/CU resident = whole grid resident at once;
// R10's 1024 blocks ran 2 passes and re-paid the wave ramp).
// Per column: hoist all 32 float4 loads into registers back-to-back (R10:
// +1.4us vs interleaved), then cvt/norm/MFMA. Gram G = X X^T via 16x16x32
// bf16 MFMA with A-frag == B-frag (identical lane mapping row/col = lane&15);
// any shared element->k permutation cancels exactly. Norms exact in f32.
// No fences/atomics (R7/R8: per-block agent-scope coherence ~ +60-110us).
__global__ __launch_bounds__(256, 2)
void ntxent_mfma(const float* __restrict__ inp, float* __restrict__ partial) {
    const int lane = threadIdx.x & 63;
    const int wv   = threadIdx.x >> 6;      // wave in block: 0..3
    const int slot = lane & 15;             // vector index = MFMA row & col
    const int kg   = lane >> 4;             // quarter-wave 0..3

    float lsum = 0.f;                       // loss sum over this wave's columns

#pragma unroll 1                            // keep one column's regs live
    for (int cc2 = 0; cc2 < 2; ++cc2) {
        const int b = blockIdx.x * 8 + 4 * cc2 + wv;   // batch column

        const f32x4* p4 = reinterpret_cast<const f32x4*>(
            inp + (size_t)slot * SLOT_STRIDE + (size_t)b * DD);

        // ---- phase 1: issue all 32 loads back-to-back into registers ----
        // chunk t covers [32t,32t+32): lane takes 32t+4kg+[0..4) and
        // 32t+16+4kg+[0..4)  ->  p4[8t+kg] and p4[8t+4+kg]
        f32x4 L[16], H[16];
#pragma unroll
        for (int t = 0; t < 16; ++t) {
            L[t] = p4[8 * t + kg];
            H[t] = p4[8 * t + 4 + kg];
        }

        // ---- phase 2: norms + bf16 convert + Gram MFMAs ----
        f32x4 acc0 = {0.f, 0.f, 0.f, 0.f};
        f32x4 acc1 = {0.f, 0.f, 0.f, 0.f};
        float n2a = 0.f, n2b = 0.f;
#pragma unroll
        for (int t = 0; t < 16; ++t) {
            const f32x4 lo = L[t];
            const f32x4 hi = H[t];
            n2a = fmaf(lo.x, lo.x, n2a);
            n2a = fmaf(lo.y, lo.y, n2a);
            n2a = fmaf(lo.z, lo.z, n2a);
            n2a = fmaf(lo.w, lo.w, n2a);
            n2b = fmaf(hi.x, hi.x, n2b);
            n2b = fmaf(hi.y, hi.y, n2b);
            n2b = fmaf(hi.z, hi.z, n2b);
            n2b = fmaf(hi.w, hi.w, n2b);
            bf16x8 f;
            f[0] = f2bf(lo.x); f[1] = f2bf(lo.y); f[2] = f2bf(lo.z); f[3] = f2bf(lo.w);
            f[4] = f2bf(hi.x); f[5] = f2bf(hi.y); f[6] = f2bf(hi.z); f[7] = f2bf(hi.w);
            if (t & 1)
                acc1 = __builtin_amdgcn_mfma_f32_16x16x32_bf16(f, f, acc1, 0, 0, 0);
            else
                acc0 = __builtin_amdgcn_mfma_f32_16x16x32_bf16(f, f, acc0, 0, 0, 0);
        }
        const f32x4 acc = acc0 + acc1;

        // exact f32 norms: lanes {slot, +16, +32, +48} cover slot fully
        float n2 = n2a + n2b;
        n2 += __shfl_xor(n2, 16);
        n2 += __shfl_xor(n2, 32);
        const float invc = 1.0f / fmaxf(sqrtf(n2), NORM_EPS);  // 1/||x_slot||

        // C/D layout (m89): lane holds G[4kg + r][slot] in acc[r].
        const float inv0 = __shfl(invc, 4 * kg);       // 1/||x_{4kg}||
        const float inv2 = __shfl(invc, 4 * kg + 2);   // 1/||x_{4kg+2}||

        const float s0 = acc[0] * inv0 * invc * INV_T;  // sim[2kg  ][slot]
        const float s2 = acc[2] * inv2 * invc * INV_T;  // sim[2kg+1][slot]

        // positives: sim[2a][2a+1] on the lane whose slot == anchor_slot+1
        const int gbase = kg << 4;
        const float pos0 = __shfl(s0, gbase + 4 * kg + 1);
        const float pos1 = __shfl(s2, gbase + 4 * kg + 3);

        float e0 = ((slot >> 1) == 2 * kg)     ? 0.f : __expf(s0 - pos0);
        float e1 = ((slot >> 1) == 2 * kg + 1) ? 0.f : __expf(s2 - pos1);
#pragma unroll
        for (int m = 1; m < 16; m <<= 1) {
            e0 += __shfl_xor(e0, m);
            e1 += __shfl_xor(e1, m);
        }
        float l = __logf(1.0f + e0) + __logf(1.0f + e1);
        l += __shfl_xor(l, 16);
        l += __shfl_xor(l, 32);   // sum over all 8 anchors for column b
        lsum += l;
    }

    __shared__ float s_wsum[4];
    if (lane == 0) s_wsum[wv] = lsum;
    __syncthreads();
    if (threadIdx.x == 0)
        partial[blockIdx.x] = s_wsum[0] + s_wsum[1] + s_wsum[2] + s_wsum[3];
}

// Sum the 512 per-block partials -> scalar loss. One wave, no LDS/sync.
__global__ __launch_bounds__(64)
void ntxent_reduce(const float* __restrict__ partial, float* __restrict__ out) {
    const int lane = threadIdx.x;
    const f32x4* pv = reinterpret_cast<const f32x4*>(partial);  // 128 vec4
    const f32x4 v0 = pv[lane];
    const f32x4 v1 = pv[lane + 64];
    float s = v0.x + v0.y + v0.z + v0.w + v1.x + v1.y + v1.z + v1.w;
#pragma unroll
    for (int m = 1; m < 64; m <<= 1) s += __shfl_xor(s, m);
    if (lane == 0) out[0] = s * (1.0f / (float)(CC * BB));
}

extern "C" void kernel_launch(void* const* d_in, const int* in_sizes, int n_in,
                              void* d_out, int out_size, void* d_ws, size_t ws_size,
                              hipStream_t stream) {
    const float* inp = (const float*)d_in[0];
    float* out      = (float*)d_out;
    float* partial  = (float*)d_ws;   // NBLK floats, fully rewritten every call
    ntxent_mfma<<<dim3(NBLK), dim3(256), 0, stream>>>(inp, partial);
    ntxent_reduce<<<dim3(1), dim3(64), 0, stream>>>(partial, out);
}